// Round 2
// baseline (269.623 us; speedup 1.0000x reference)
//
#include <hip/hip_runtime.h>

#define IN_F 4096
#define OUT_F 11008
#define BATCH 64
#define KSPLIT 8
#define STEPS (IN_F / 64 / KSPLIT)   // 8 K-steps of 64 per block

typedef int v4i __attribute__((ext_vector_type(4)));
typedef signed char i8;

// pack 4 int32 (each in [-128,127]) into one dword of 4 int8 lanes
__device__ __forceinline__ int pack4(int a0, int a1, int a2, int a3) {
    return (a0 & 0xff) | ((a1 & 0xff) << 8) | ((a2 & 0xff) << 16) |
           ((unsigned)a3 << 24);
}

// ---------------------------------------------------------------------------
// Pre-kernel 1: dynamic per-row int8 quantization of x, scattered directly
// into MFMA A-fragment order for v_mfma_i32_16x16x64_i8:
//   A[m = lane&15][k = (lane>>4)*16 + j], j in [0,16)
// ws layout: byte index ((kc*256 + mt*64 + lane)*16 + j)
//   where b = mt*16 + (lane&15), i = kc*64 + (lane>>4)*16 + j
// ---------------------------------------------------------------------------
__global__ __launch_bounds__(256)
void quant_x_kernel(const float* __restrict__ x, i8* __restrict__ xq,
                    float* __restrict__ xscale)
{
    const int b = blockIdx.x;      // batch row, 64 blocks
    const int t = threadIdx.x;     // 256 threads, 16 floats each
    const float* xr = x + (size_t)b * IN_F;
    const int i0 = t * 16;

    float vals[16];
    float m = 0.0f;
#pragma unroll
    for (int j = 0; j < 16; ++j) {
        vals[j] = xr[i0 + j];
        m = fmaxf(m, fabsf(vals[j]));
    }

    __shared__ float red[256];
    red[t] = m;
    __syncthreads();
    for (int s = 128; s > 0; s >>= 1) {
        if (t < s) red[t] = fmaxf(red[t], red[t + s]);
        __syncthreads();
    }
    const float amax = red[0];
    const float inv = (amax > 0.0f) ? (127.0f / amax) : 0.0f;
    if (t == 0) xscale[b] = (amax > 0.0f) ? (amax / 127.0f) : 1.0f;

    const int kc   = i0 >> 6;
    const int quad = (i0 >> 4) & 3;
    const int mt   = b >> 4;
    const int lane = (b & 15) | (quad << 4);

    i8 q[16];
#pragma unroll
    for (int j = 0; j < 16; ++j) {
        float r = rintf(vals[j] * inv);
        r = fminf(127.0f, fmaxf(-127.0f, r));
        q[j] = (i8)(int)r;
    }
    v4i* dst = (v4i*)(xq + ((size_t)(kc * 256 + mt * 64 + lane) * 16));
    *dst = *(const v4i*)q;
}

// ---------------------------------------------------------------------------
// Pre-kernel 2: out[b][o] = bias[o]  (atomic K-split partials add onto this;
// also overwrites the 0xAA poison)
// ---------------------------------------------------------------------------
__global__ __launch_bounds__(256)
void init_out_kernel(const float* __restrict__ bias, float* __restrict__ out)
{
    const int o = blockIdx.x * 256 + threadIdx.x;  // gridDim.x = 43 -> exact
    const int b = blockIdx.y;
    out[(size_t)b * OUT_F + o] = bias[o];
}

// ---------------------------------------------------------------------------
// Main GEMM. Weights arrive as INT32 (harness materializes integer inputs as
// int32!) — 180 MB stream, the memory floor. Per block: M=64 (whole batch),
// N=128 (4 waves x 2 n-tiles), K-chunk = 8 steps x 64. No LDS, no barriers:
// A fragments pre-scattered in ws (L2-hot), raw int32 weights load
// global->VGPR, packed to i8 in-register, int8 MFMA, exact int32 accumulate,
// fp32 scale + atomicAdd epilogue onto bias-initialized out.
// ---------------------------------------------------------------------------
__global__ __launch_bounds__(256)
void gemm_kernel(const int* __restrict__ wq, const i8* __restrict__ xq,
                 const float* __restrict__ xscale,
                 const float* __restrict__ wscale,
                 float* __restrict__ out)
{
    const int lane  = threadIdx.x & 63;
    const int wave  = threadIdx.x >> 6;
    const int laneN = lane & 15;
    const int quad  = lane >> 4;

    const int n0  = blockIdx.x * 128;
    const int kc0 = blockIdx.y * STEPS;       // this block's K chunk

    const int oA = n0 + wave * 32 + laneN;    // n-tile 0 of this wave
    const int oB = oA + 16;                   // n-tile 1

    // B fragment: B[k][n], n = lane&15, k = quad*16 + j -> lane reads 16
    // consecutive int32 of weight row o at each K step.
    const int kbase = kc0 * 64 + quad * 16;
    const int* pWA = wq + (size_t)oA * IN_F + kbase;
    const int* pWB = wq + (size_t)oB * IN_F + kbase;
    const v4i* pA  = (const v4i*)xq + (size_t)kc0 * 256 + lane;

    v4i acc[4][2];
#pragma unroll
    for (int mt = 0; mt < 4; ++mt)
#pragma unroll
        for (int nt = 0; nt < 2; ++nt)
            acc[mt][nt] = (v4i){0, 0, 0, 0};

    v4i rA[2][4];   // raw int32 weights for next step: [n-tile][4 x v4i]
    v4i aC[4], aN[4], bC[2];

    // prologue: raw weights + A fragments for step 0
#pragma unroll
    for (int r = 0; r < 4; ++r) {
        rA[0][r] = ((const v4i*)pWA)[r];
        rA[1][r] = ((const v4i*)pWB)[r];
    }
#pragma unroll
    for (int mt = 0; mt < 4; ++mt) aC[mt] = pA[mt * 64];
#pragma unroll
    for (int t = 0; t < 2; ++t)
        bC[t] = (v4i){pack4(rA[t][0][0], rA[t][0][1], rA[t][0][2], rA[t][0][3]),
                      pack4(rA[t][1][0], rA[t][1][1], rA[t][1][2], rA[t][1][3]),
                      pack4(rA[t][2][0], rA[t][2][1], rA[t][2][2], rA[t][2][3]),
                      pack4(rA[t][3][0], rA[t][3][1], rA[t][3][2], rA[t][3][3])};

#pragma unroll
    for (int s = 0; s < STEPS; ++s) {
        if (s + 1 < STEPS) {
            const v4i* nWA = (const v4i*)(pWA + (size_t)(s + 1) * 64);
            const v4i* nWB = (const v4i*)(pWB + (size_t)(s + 1) * 64);
#pragma unroll
            for (int r = 0; r < 4; ++r) {
                rA[0][r] = nWA[r];
                rA[1][r] = nWB[r];
            }
            const v4i* nA = pA + (size_t)(s + 1) * 256;
#pragma unroll
            for (int mt = 0; mt < 4; ++mt) aN[mt] = nA[mt * 64];
        }
#pragma unroll
        for (int mt = 0; mt < 4; ++mt) {
            acc[mt][0] = __builtin_amdgcn_mfma_i32_16x16x64_i8(aC[mt], bC[0], acc[mt][0], 0, 0, 0);
            acc[mt][1] = __builtin_amdgcn_mfma_i32_16x16x64_i8(aC[mt], bC[1], acc[mt][1], 0, 0, 0);
        }
        if (s + 1 < STEPS) {
#pragma unroll
            for (int t = 0; t < 2; ++t)
                bC[t] = (v4i){pack4(rA[t][0][0], rA[t][0][1], rA[t][0][2], rA[t][0][3]),
                              pack4(rA[t][1][0], rA[t][1][1], rA[t][1][2], rA[t][1][3]),
                              pack4(rA[t][2][0], rA[t][2][1], rA[t][2][2], rA[t][2][3]),
                              pack4(rA[t][3][0], rA[t][3][1], rA[t][3][2], rA[t][3][3])};
#pragma unroll
            for (int mt = 0; mt < 4; ++mt) aC[mt] = aN[mt];
        }
    }

    // Epilogue. C/D layout: col = lane&15 (n), row = quad*4 + reg (m).
    const float wsA = wscale[oA];
    const float wsB = wscale[oB];
    const int rbase = quad * 4;
#pragma unroll
    for (int mt = 0; mt < 4; ++mt) {
#pragma unroll
        for (int r = 0; r < 4; ++r) {
            const int brow = mt * 16 + rbase + r;
            const float xs = xscale[brow];
            atomicAdd(&out[(size_t)brow * OUT_F + oA], (float)acc[mt][0][r] * xs * wsA);
            atomicAdd(&out[(size_t)brow * OUT_F + oB], (float)acc[mt][1][r] * xs * wsB);
        }
    }
}

extern "C" void kernel_launch(void* const* d_in, const int* in_sizes, int n_in,
                              void* d_out, int out_size, void* d_ws, size_t ws_size,
                              hipStream_t stream)
{
    const float* x      = (const float*)d_in[0];
    const int*   wq     = (const int*)d_in[1];      // int inputs arrive as int32
    const float* wscale = (const float*)d_in[2];
    const float* bias   = (const float*)d_in[3];
    float* out = (float*)d_out;

    i8*    xq     = (i8*)d_ws;                                   // 256 KB
    float* xscale = (float*)((char*)d_ws + (size_t)BATCH * IN_F); // 64 floats

    quant_x_kernel<<<BATCH, 256, 0, stream>>>(x, xq, xscale);
    init_out_kernel<<<dim3(OUT_F / 256, BATCH), 256, 0, stream>>>(bias, out);
    gemm_kernel<<<dim3(OUT_F / 128, KSPLIT), 256, 0, stream>>>(wq, xq, xscale, wscale, out);
}